// Round 12
// baseline (346.947 us; speedup 1.0000x reference)
//
#include <hip/hip_runtime.h>

#define HEADS 4
#define DHEAD 128
#define DIM   512
#define NTOK  1024     // 32*32
#define BATCH 16
#define OCH   1536     // 3 * HEADS * DHEAD

typedef unsigned short u16;
typedef short bf16x8 __attribute__((ext_vector_type(8)));   // 8 bf16 = 4 VGPR
typedef float f32x4  __attribute__((ext_vector_type(4)));

struct alignas(8) us4 { u16 x, y, z, w; };

static __device__ __forceinline__ u16 f2bf(float f) {
    unsigned int u = __float_as_uint(f);
    u = (u + 0x7FFFu + ((u >> 16) & 1u)) >> 16;   // RNE
    return (u16)u;
}
static __device__ __forceinline__ float bf2f(u16 h) {
    return __uint_as_float(((unsigned int)h) << 16);
}

// ---------------------------------------------------------------------------
// Prep 1: Ft = F transposed+converted: [b][n=1024][c=512] bf16 hi/lo.
// ---------------------------------------------------------------------------
__global__ __launch_bounds__(256)
void prep_ft(const float* __restrict__ F, u16* __restrict__ fthi, u16* __restrict__ ftlo)
{
    __shared__ float T[32][33];
    const int n0 = blockIdx.x * 32;
    const int c0 = blockIdx.y * 32;
    const int b  = blockIdx.z;
    const int tid = threadIdx.x;

    {
        const int c  = tid >> 3;
        const int n4 = (tid & 7) * 4;
        const float4 f4 = *(const float4*)(&F[((size_t)b * DIM + c0 + c) * NTOK + n0 + n4]);
        T[c][n4 + 0] = f4.x; T[c][n4 + 1] = f4.y; T[c][n4 + 2] = f4.z; T[c][n4 + 3] = f4.w;
    }
    __syncthreads();
    {
        const int n  = tid >> 3;
        const int c4 = (tid & 7) * 4;
        us4 H, L;
        float v0 = T[c4 + 0][n], v1 = T[c4 + 1][n], v2 = T[c4 + 2][n], v3 = T[c4 + 3][n];
        H.x = f2bf(v0); L.x = f2bf(v0 - bf2f(H.x));
        H.y = f2bf(v1); L.y = f2bf(v1 - bf2f(H.y));
        H.z = f2bf(v2); L.z = f2bf(v2 - bf2f(H.z));
        H.w = f2bf(v3); L.w = f2bf(v3 - bf2f(H.w));
        const size_t o = ((size_t)b * NTOK + n0 + n) * DIM + c0 + c4;
        *(us4*)&fthi[o] = H;
        *(us4*)&ftlo[o] = L;
    }
}

// ---------------------------------------------------------------------------
// Prep 2: Wb = W converted: [o=1536][c=512] bf16 hi/lo.
// ---------------------------------------------------------------------------
__global__ __launch_bounds__(256)
void prep_w(const float* __restrict__ W, u16* __restrict__ wbhi, u16* __restrict__ wblo)
{
    const size_t idx = ((size_t)blockIdx.x * 256 + threadIdx.x) * 8;
    const float4 a = *(const float4*)(&W[idx]);
    const float4 b = *(const float4*)(&W[idx + 4]);
    float v[8] = {a.x, a.y, a.z, a.w, b.x, b.y, b.z, b.w};
    u16 H[8], L[8];
#pragma unroll
    for (int j = 0; j < 8; ++j) {
        H[j] = f2bf(v[j]);
        L[j] = f2bf(v[j] - bf2f(H[j]));
    }
    *(bf16x8*)&wbhi[idx] = *(bf16x8*)H;
    *(bf16x8*)&wblo[idx] = *(bf16x8*)L;
}

// ---------------------------------------------------------------------------
// Kernel 1: QKV projection, split-bf16 MFMA GEMM + register prefetch.
// (validated round 9/10 — unchanged this round)
// ---------------------------------------------------------------------------
__global__ __launch_bounds__(256, 2)
void qkv_mfma(const u16* __restrict__ fthi, const u16* __restrict__ ftlo,
              const u16* __restrict__ wbhi, const u16* __restrict__ wblo,
              const float* __restrict__ EH, const float* __restrict__ EW,
              u16* __restrict__ qhi, u16* __restrict__ qlo,
              u16* __restrict__ khi, u16* __restrict__ klo,
              u16* __restrict__ vtg)
{
    __shared__ u16 smem[16384];            // 32 KB
    u16* Ah = smem;                        // [64][64] swizzled (token x k)
    u16* Al = smem + 4096;
    u16* Bh = smem + 8192;                 // [64][64] swizzled (o x k)
    u16* Bl = smem + 12288;
    float* Od = (float*)smem;              // epilogue reuse [64][68] f32

    const int tid  = threadIdx.x;
    const int lane = tid & 63;
    const int wave = tid >> 6;
    const int l15  = lane & 15;
    const int lg   = lane >> 4;
    const int wm   = wave >> 1;
    const int wn   = wave & 1;

    const int ii = blockIdx.x * 64;
    const int oo = blockIdx.y * 64;
    const int b  = blockIdx.z;
    const size_t fbase = (size_t)b * NTOK * DIM;

    const int jrow = tid >> 3;
    const int dc   = (tid & 7) * 8;
    const int ld0  = jrow * 64 + (dc ^ ((jrow & 7) << 3));   // +2048 per u
    const size_t ga0 = fbase + (size_t)(ii + jrow) * DIM + dc;
    const size_t gb0 = (size_t)(oo + jrow) * DIM + dc;

    f32x4 acc[2][2];
#pragma unroll
    for (int mf = 0; mf < 2; ++mf)
#pragma unroll
        for (int nf = 0; nf < 2; ++nf) { acc[mf][nf][0] = 0.f; acc[mf][nf][1] = 0.f; acc[mf][nf][2] = 0.f; acc[mf][nf][3] = 0.f; }

    bf16x8 pah[2], pal[2], pbh[2], pbl[2];
#pragma unroll
    for (int u = 0; u < 2; ++u) {
        pah[u] = *(const bf16x8*)(fthi + ga0 + (size_t)u * 32 * DIM);
        pal[u] = *(const bf16x8*)(ftlo + ga0 + (size_t)u * 32 * DIM);
        pbh[u] = *(const bf16x8*)(wbhi + gb0 + (size_t)u * 32 * DIM);
        pbl[u] = *(const bf16x8*)(wblo + gb0 + (size_t)u * 32 * DIM);
    }
#pragma unroll
    for (int u = 0; u < 2; ++u) {
        *(bf16x8*)&Ah[ld0 + 2048 * u] = pah[u];
        *(bf16x8*)&Al[ld0 + 2048 * u] = pal[u];
        *(bf16x8*)&Bh[ld0 + 2048 * u] = pbh[u];
        *(bf16x8*)&Bl[ld0 + 2048 * u] = pbl[u];
    }
    __syncthreads();

    for (int kt = 0; kt < DIM; kt += 64) {
        if (kt < DIM - 64) {
#pragma unroll
            for (int u = 0; u < 2; ++u) {
                pah[u] = *(const bf16x8*)(fthi + ga0 + kt + 64 + (size_t)u * 32 * DIM);
                pal[u] = *(const bf16x8*)(ftlo + ga0 + kt + 64 + (size_t)u * 32 * DIM);
                pbh[u] = *(const bf16x8*)(wbhi + gb0 + kt + 64 + (size_t)u * 32 * DIM);
                pbl[u] = *(const bf16x8*)(wblo + gb0 + kt + 64 + (size_t)u * 32 * DIM);
            }
        }

#pragma unroll
        for (int kc = 0; kc < 2; ++kc) {
            const int ko = kc * 32 + lg * 8;
            bf16x8 af_h[2], af_l[2], bf_h[2], bf_l[2];
#pragma unroll
            for (int mf = 0; mf < 2; ++mf) {
                const int ar = wm * 32 + mf * 16 + l15;
                const int off = ar * 64 + (ko ^ ((ar & 7) << 3));
                af_h[mf] = *(const bf16x8*)&Ah[off];
                af_l[mf] = *(const bf16x8*)&Al[off];
            }
#pragma unroll
            for (int nf = 0; nf < 2; ++nf) {
                const int br = wn * 32 + nf * 16 + l15;
                const int off = br * 64 + (ko ^ ((br & 7) << 3));
                bf_h[nf] = *(const bf16x8*)&Bh[off];
                bf_l[nf] = *(const bf16x8*)&Bl[off];
            }
#pragma unroll
            for (int mf = 0; mf < 2; ++mf)
#pragma unroll
                for (int nf = 0; nf < 2; ++nf) {
                    acc[mf][nf] = __builtin_amdgcn_mfma_f32_16x16x32_bf16(af_h[mf], bf_h[nf], acc[mf][nf], 0, 0, 0);
                    acc[mf][nf] = __builtin_amdgcn_mfma_f32_16x16x32_bf16(af_h[mf], bf_l[nf], acc[mf][nf], 0, 0, 0);
                    acc[mf][nf] = __builtin_amdgcn_mfma_f32_16x16x32_bf16(af_l[mf], bf_h[nf], acc[mf][nf], 0, 0, 0);
                }
        }
        __syncthreads();
        if (kt < DIM - 64) {
#pragma unroll
            for (int u = 0; u < 2; ++u) {
                *(bf16x8*)&Ah[ld0 + 2048 * u] = pah[u];
                *(bf16x8*)&Al[ld0 + 2048 * u] = pal[u];
                *(bf16x8*)&Bh[ld0 + 2048 * u] = pbh[u];
                *(bf16x8*)&Bl[ld0 + 2048 * u] = pbl[u];
            }
        }
        __syncthreads();
    }

#pragma unroll
    for (int mf = 0; mf < 2; ++mf)
#pragma unroll
        for (int nf = 0; nf < 2; ++nf)
#pragma unroll
            for (int r = 0; r < 4; ++r)
                Od[(wm * 32 + mf * 16 + lg * 4 + r) * 68 + wn * 32 + nf * 16 + l15] = acc[mf][nf][r];
    __syncthreads();

    const int s  = oo >> 9;
    const int h  = (oo >> 7) & 3;
    const int d0 = oo & 127;
    const int bh = b * HEADS + h;
    const float scale = 0.08838834764831845f;   // 128^-0.5

    if (s == 2) {
#pragma unroll
        for (int u = 0; u < 2; ++u) {
            const int idx = tid + 256 * u;
            const int dr = idx >> 3;
            const int tc = (idx & 7) * 8;
            u16 P[8];
#pragma unroll
            for (int j = 0; j < 8; ++j)
                P[j] = f2bf(Od[(tc + j) * 68 + dr]);
            *(bf16x8*)&vtg[((size_t)bh * DHEAD + d0 + dr) * NTOK + ii + tc] = *(bf16x8*)P;
        }
    } else {
        u16* hi = s ? khi : qhi;
        u16* lo = s ? klo : qlo;
#pragma unroll
        for (int u = 0; u < 2; ++u) {
            const int idx = tid + 256 * u;
            const int tr = idx >> 3;
            const int dcc = (idx & 7) * 8;
            const int i  = ii + tr;
            float v[8];
            const float4 p0 = *(const float4*)&Od[tr * 68 + dcc];
            const float4 p1 = *(const float4*)&Od[tr * 68 + dcc + 4];
            v[0] = p0.x; v[1] = p0.y; v[2] = p0.z; v[3] = p0.w;
            v[4] = p1.x; v[5] = p1.y; v[6] = p1.z; v[7] = p1.w;
            if (s == 0) {
#pragma unroll
                for (int j = 0; j < 8; ++j) v[j] *= scale;
            } else {
                const float* eh = &EH[(i >> 5) * DHEAD + d0 + dcc];
                const float* ew = &EW[(i & 31) * DHEAD + d0 + dcc];
                const float4 e0 = *(const float4*)eh, e1 = *(const float4*)(eh + 4);
                const float4 w0 = *(const float4*)ew, w1 = *(const float4*)(ew + 4);
                v[0] += e0.x + w0.x; v[1] += e0.y + w0.y; v[2] += e0.z + w0.z; v[3] += e0.w + w0.w;
                v[4] += e1.x + w1.x; v[5] += e1.y + w1.y; v[6] += e1.z + w1.z; v[7] += e1.w + w1.w;
            }
            u16 H[8], L[8];
#pragma unroll
            for (int j = 0; j < 8; ++j) {
                H[j] = f2bf(v[j]);
                L[j] = f2bf(v[j] - bf2f(H[j]));
            }
            const size_t o = ((size_t)bh * NTOK + i) * DHEAD + d0 + dcc;
            *(bf16x8*)&hi[o] = *(bf16x8*)H;
            *(bf16x8*)&lo[o] = *(bf16x8*)L;
        }
    }
}

// ---------------------------------------------------------------------------
// Kernel 2: MFMA flash attention — QB=128, 8 waves/block, 512 threads.
// Grid (bh, qtile): linear%8 = bh%8 -> one XCD per bh (K/V L2 locality).
// 64 KB LDS -> 2 blocks/CU = 16 waves/CU (2x round-10 occupancy).
// Per-wave math identical to the round-8-validated kernel.
// ---------------------------------------------------------------------------
#define QB 128
#define KB 64

__global__ __launch_bounds__(512, 4)
void attn_mfma(const u16* __restrict__ qh, const u16* __restrict__ ql,
               const u16* __restrict__ kh, const u16* __restrict__ kl,
               const u16* __restrict__ vtg, float* __restrict__ out)
{
    __shared__ u16 smem[32768];            // 65536 B -> 2 blocks/CU
    u16* Kh = smem;                        // [64][128] swizzled
    u16* Kl = smem + 8192;
    u16* Vt = smem + 16384;                // [128][64] swizzled
    u16* Pl = smem + 24576;                // 8 waves x [16][64] swizzled
    float* Od = (float*)smem;              // epilogue reuse [128][72] (half-pass)

    const int tid  = threadIdx.x;
    const int lane = tid & 63;
    const int wave = tid >> 6;             // 0..7
    const int l15  = lane & 15;
    const int lg   = lane >> 4;

    const int bh = blockIdx.x;
    const int ii = blockIdx.y * QB;
    const size_t base = (size_t)bh * NTOK * DHEAD;   // also vt base

    // staging geometry (512 threads): K slot=tid+512u -> row kj+32u; V -> row vd+64u
    const int kj  = tid >> 4;              // 0..31
    const int kdc = (tid & 15) * 8;
    const int vd  = tid >> 3;              // 0..63
    const int vjc = (tid & 7) * 8;
    const int ldk0 = kj * DHEAD + (kdc ^ ((kj & 7) << 3));   // +4096 per u
    const int ldv0 = vd * KB   + (vjc ^ ((vd & 7) << 3));    // +4096 per u
    const size_t gk0 = base + (size_t)kj * DHEAD + kdc;      // + jt*8192 + 4096u
    const size_t gv0 = base + (size_t)vd * NTOK + vjc;       // + jt*64 + 65536u

    bf16x8 qfh[4], qfl[4];
    {
        const size_t qoff = base + (size_t)(ii + wave * 16 + l15) * DHEAD + lg * 8;
#pragma unroll
        for (int kc = 0; kc < 4; ++kc) {
            qfh[kc] = *(const bf16x8*)(qh + qoff + kc * 32);
            qfl[kc] = *(const bf16x8*)(ql + qoff + kc * 32);
        }
    }

    f32x4 o[8];
#pragma unroll
    for (int n = 0; n < 8; ++n) { o[n][0] = 0.f; o[n][1] = 0.f; o[n][2] = 0.f; o[n][3] = 0.f; }
    float mrow[4], lrow[4];
#pragma unroll
    for (int r = 0; r < 4; ++r) { mrow[r] = -3.0e38f; lrow[r] = 0.f; }

    bf16x8 pkh[2], pkl[2], pv[2];
    // prologue: load + stage jt=0
#pragma unroll
    for (int u = 0; u < 2; ++u) {
        pkh[u] = *(const bf16x8*)(kh  + gk0 + 4096 * u);
        pkl[u] = *(const bf16x8*)(kl  + gk0 + 4096 * u);
        pv[u]  = *(const bf16x8*)(vtg + gv0 + 65536 * (size_t)u);
    }
#pragma unroll
    for (int u = 0; u < 2; ++u) {
        *(bf16x8*)&Kh[ldk0 + 4096 * u] = pkh[u];
        *(bf16x8*)&Kl[ldk0 + 4096 * u] = pkl[u];
        *(bf16x8*)&Vt[ldv0 + 4096 * u] = pv[u];
    }
    __syncthreads();

    for (int jt = 0; jt < NTOK / KB; ++jt) {
        if (jt < NTOK / KB - 1) {
            const size_t gk = gk0 + (size_t)(jt + 1) * 8192;
            const size_t gv = gv0 + (size_t)(jt + 1) * 64;
#pragma unroll
            for (int u = 0; u < 2; ++u) {
                pkh[u] = *(const bf16x8*)(kh  + gk + 4096 * u);
                pkl[u] = *(const bf16x8*)(kl  + gk + 4096 * u);
                pv[u]  = *(const bf16x8*)(vtg + gv + 65536 * (size_t)u);
            }
        }

        // S = Q K'^T  (split bf16)
        f32x4 s[4];
        __builtin_amdgcn_s_setprio(1);
#pragma unroll
        for (int n = 0; n < 4; ++n) {
            f32x4 acc = {0.f, 0.f, 0.f, 0.f};
            const int j  = n * 16 + l15;
            const int ro = j * DHEAD;
            const int sw = (j & 7) << 3;
#pragma unroll
            for (int kc = 0; kc < 4; ++kc) {
                const int off = ro + ((kc * 32 + lg * 8) ^ sw);
                const bf16x8 kb = *(const bf16x8*)&Kh[off];
                const bf16x8 lb = *(const bf16x8*)&Kl[off];
                acc = __builtin_amdgcn_mfma_f32_16x16x32_bf16(qfh[kc], kb, acc, 0, 0, 0);
                acc = __builtin_amdgcn_mfma_f32_16x16x32_bf16(qfh[kc], lb, acc, 0, 0, 0);
                acc = __builtin_amdgcn_mfma_f32_16x16x32_bf16(qfl[kc], kb, acc, 0, 0, 0);
            }
            s[n] = acc;
        }
        __builtin_amdgcn_s_setprio(0);

        // online softmax (per-wave, 16 rows)
        float tmax[4];
#pragma unroll
        for (int r = 0; r < 4; ++r)
            tmax[r] = fmaxf(fmaxf(s[0][r], s[1][r]), fmaxf(s[2][r], s[3][r]));
#pragma unroll
        for (int off = 1; off < 16; off <<= 1)
#pragma unroll
            for (int r = 0; r < 4; ++r)
                tmax[r] = fmaxf(tmax[r], __shfl_xor(tmax[r], off));

        float fr[4], psum[4];
#pragma unroll
        for (int r = 0; r < 4; ++r) {
            const float mn = fmaxf(mrow[r], tmax[r]);
            fr[r] = __expf(mrow[r] - mn);
            mrow[r] = mn;
            psum[r] = 0.f;
        }
        const int pbase = wave * 1024;
#pragma unroll
        for (int n = 0; n < 4; ++n)
#pragma unroll
            for (int r = 0; r < 4; ++r) {
                const float p = __expf(s[n][r] - mrow[r]);
                psum[r] += p;
                const int row = lg * 4 + r;
                Pl[pbase + row * KB + ((n * 16 + l15) ^ ((row & 7) << 3))] = f2bf(p);
            }
#pragma unroll
        for (int off = 1; off < 16; off <<= 1)
#pragma unroll
            for (int r = 0; r < 4; ++r)
                psum[r] += __shfl_xor(psum[r], off);
#pragma unroll
        for (int r = 0; r < 4; ++r) lrow[r] = lrow[r] * fr[r] + psum[r];
#pragma unroll
        for (int n = 0; n < 8; ++n)
#pragma unroll
            for (int r = 0; r < 4; ++r) o[n][r] *= fr[r];

        // PV
        const bf16x8 pf0 = *(const bf16x8*)&Pl[pbase + l15 * KB + ((lg * 8) ^ ((l15 & 7) << 3))];
        const bf16x8 pf1 = *(const bf16x8*)&Pl[pbase + l15 * KB + ((32 + lg * 8) ^ ((l15 & 7) << 3))];
        __builtin_amdgcn_s_setprio(1);
#pragma unroll
        for (int nd = 0; nd < 8; ++nd) {
            const int d  = nd * 16 + l15;
            const int vo = d * KB;
            const int sw = (d & 7) << 3;
            o[nd] = __builtin_amdgcn_mfma_f32_16x16x32_bf16(
                        pf0, *(const bf16x8*)&Vt[vo + ((lg * 8) ^ sw)], o[nd], 0, 0, 0);
            o[nd] = __builtin_amdgcn_mfma_f32_16x16x32_bf16(
                        pf1, *(const bf16x8*)&Vt[vo + ((32 + lg * 8) ^ sw)], o[nd], 0, 0, 0);
        }
        __builtin_amdgcn_s_setprio(0);

        __syncthreads();                   // all waves done reading K/V/P LDS
        if (jt < NTOK / KB - 1) {
#pragma unroll
            for (int u = 0; u < 2; ++u) {
                *(bf16x8*)&Kh[ldk0 + 4096 * u] = pkh[u];
                *(bf16x8*)&Kl[ldk0 + 4096 * u] = pkl[u];
                *(bf16x8*)&Vt[ldv0 + 4096 * u] = pv[u];
            }
        }
        __syncthreads();                   // next tile visible
    }

    // epilogue: normalize + transpose via LDS in TWO i-halves (Od = [128][72] f32)
    __syncthreads();
    float invl[4];
#pragma unroll
    for (int r = 0; r < 4; ++r) invl[r] = 1.0f / lrow[r];

    const int wh = wave >> 2;              // which half this wave's rows belong to
    const int wl = wave & 3;
    const int bb = bh >> 2, hd = bh & 3;
    float* dst = out + ((size_t)bb * 512 + hd * DHEAD) * NTOK + ii;

#pragma unroll
    for (int half = 0; half < 2; ++half) {
        if (wh == half) {
#pragma unroll
            for (int nd = 0; nd < 8; ++nd)
#pragma unroll
                for (int r = 0; r < 4; ++r)
                    Od[(nd * 16 + l15) * 72 + wl * 16 + lg * 4 + r] = o[nd][r] * invl[r];
        }
        __syncthreads();
#pragma unroll
        for (int u = 0; u < 2; ++u) {
            const int slot = tid + 512 * u;
            const int d  = slot >> 3;
            const int jc = (slot & 7) * 8;
            *(float4*)(dst + (size_t)d * NTOK + half * 64 + jc)     = *(const float4*)&Od[d * 72 + jc];
            *(float4*)(dst + (size_t)d * NTOK + half * 64 + jc + 4) = *(const float4*)&Od[d * 72 + jc + 4];
        }
        __syncthreads();
    }
}

// ---------------------------------------------------------------------------
extern "C" void kernel_launch(void* const* d_in, const int* in_sizes, int n_in,
                              void* d_out, int out_size, void* d_ws, size_t ws_size,
                              hipStream_t stream)
{
    (void)in_sizes; (void)n_in; (void)out_size; (void)ws_size;
    const float* fmap  = (const float*)d_in[0];
    const float* w_qkv = (const float*)d_in[1];
    const float* eh    = (const float*)d_in[2];
    const float* ew    = (const float*)d_in[3];
    float* out = (float*)d_out;

    const size_t per = (size_t)BATCH * HEADS * NTOK * DHEAD;   // 8.39M elems
    u16* qhi  = (u16*)d_ws;
    u16* qlo  = qhi + per;
    u16* khi  = qlo + per;
    u16* klo  = khi + per;
    u16* vtg  = klo + per;
    u16* fthi = vtg + per;
    u16* ftlo = fthi + per;
    u16* wbhi = ftlo + per;
    u16* wblo = wbhi + (size_t)OCH * DIM;   // total ~120.6 MB

    hipLaunchKernelGGL(prep_ft, dim3(NTOK / 32, DIM / 32, BATCH), dim3(256), 0, stream,
                       fmap, fthi, ftlo);
    hipLaunchKernelGGL(prep_w, dim3((OCH * DIM) / (256 * 8)), dim3(256), 0, stream,
                       w_qkv, wbhi, wblo);
    hipLaunchKernelGGL(qkv_mfma, dim3(NTOK / 64, OCH / 64, BATCH), dim3(256), 0, stream,
                       fthi, ftlo, wbhi, wblo, eh, ew, qhi, qlo, khi, klo, vtg);
    hipLaunchKernelGGL(attn_mfma, dim3(BATCH * HEADS, NTOK / QB), dim3(512), 0, stream,
                       qhi, qlo, khi, klo, vtg, out);
}